// Round 4
// baseline (141.088 us; speedup 1.0000x reference)
//
#include <hip/hip_runtime.h>

// GNNCriticEncoder fused kernel v6 (MI355X / gfx950)
// v5 got no data (container infra failure x2). v6 = v5 + __has_builtin guards on the
// transcendental builtins (compile-robustness hedge), otherwise identical.
// History:
//  v4 failed (absmax 0.21, stray huge outputs): diagnosis = TRANS-op hazard.
//  v_exp_f32 / v_rcp_f32 are transcendental ops with software-managed wait states
//  before a dependent VALU read; inside inline asm the compiler's hazard recognizer
//  can't see them and omits the s_nops -> consumers read stale registers.
//  Fix: compiler-visible builtins (hazard-handled by the backend).
// Carried wins over v2 (138.3 us baseline):
//  - P0 obs scatter: float4 loads + b64 LDS stores (4 iters, magic-div)
//  - softmax in exp2 domain: alphas scaled by log2e once, alive-mask folded into ad8,
//    no max-subtract (alphas O(1)-bounded), hw rcp
// ws = exactly 81920 B (do not exceed).

#define NTOK 32
#define EMB  128
#define OBSL 1056
#define XSTR 136   // s_xh row stride in bf16: 272 B (16B-aligned rows)

typedef __attribute__((ext_vector_type(8))) short  short8;   // 8 x bf16 MFMA A/B frag
typedef __attribute__((ext_vector_type(4))) float  floatx4;  // MFMA C/D frag
typedef __attribute__((ext_vector_type(2))) unsigned uint2v;

__device__ __forceinline__ short f2bf(float f) {             // scalar RNE (prep kernel only)
  union { float f; unsigned u; } v; v.f = f;
  unsigned r = (v.u + 0x7fffu + ((v.u >> 16) & 1u)) >> 16;
  return (short)(unsigned short)r;
}
// HW packed fp32->bf16 (RNE): plain VALU op, safe in inline asm
__device__ __forceinline__ unsigned pk2(float a, float b) {
  unsigned r; asm("v_cvt_pk_bf16_f32 %0, %1, %2" : "=v"(r) : "v"(a), "v"(b)); return r;
}
__device__ __forceinline__ float exp2_hw(float x) {
#if __has_builtin(__builtin_amdgcn_exp2f)
  return __builtin_amdgcn_exp2f(x);
#else
  return exp2f(x);                                  // ocml, lowers to v_exp_f32 + denorm guard
#endif
}
__device__ __forceinline__ float rcp_hw(float x) {
#if __has_builtin(__builtin_amdgcn_rcpf)
  return __builtin_amdgcn_rcpf(x);
#else
  return 1.0f / x;                                  // v2 used full divide; fine
#endif
}
__device__ __forceinline__ float elu1(float v) { return v > 0.f ? v : __expf(v) - 1.f; }
__device__ __forceinline__ floatx4 mfma16(short8 a, short8 b, floatx4 c) {
  return __builtin_amdgcn_mfma_f32_16x16x32_bf16(a, b, c, 0, 0, 0);
}

// ws layout (bf16): [0,8192) embT[e][k] (k<40 Wv, else Wp) | [8192,24576) wT0[e][k] | [24576,40960) wT1[e][k]
// Total: 40960 shorts = exactly 81920 B. DO NOT EXCEED (ws_size appears to be 80 KiB).
__global__ void prep_weights(const float* __restrict__ Wv, const float* __restrict__ Wp,
                             const float* __restrict__ w0, const float* __restrict__ w1,
                             short* __restrict__ ws) {
  int idx = blockIdx.x * 256 + threadIdx.x;          // 160 blocks x 256 = 40960
  if (idx < 8192) {
    int e = idx >> 6, k = idx & 63;
    float v = (k < 40) ? Wv[(size_t)k * EMB + e] : Wp[(size_t)(k - 40) * EMB + e];
    ws[idx] = f2bf(v);
  } else if (idx < 24576) {
    int t = idx - 8192; int e = t >> 7, k = t & 127;
    ws[idx] = f2bf(w0[(size_t)k * EMB + e]);
  } else {
    int t = idx - 24576; int e = t >> 7, k = t & 127;
    ws[idx] = f2bf(w1[(size_t)k * EMB + e]);
  }
}

__global__ __launch_bounds__(256, 4) void gnn_fused(
    const float* __restrict__ obs,
    const float* __restrict__ bv, const float* __restrict__ bp,
    const float* __restrict__ as0, const float* __restrict__ ad0,
    const float* __restrict__ as1, const float* __restrict__ ad1,
    const short* __restrict__ wsb,
    float* __restrict__ out)
{
  __shared__ __align__(16) short s_xh[EMB * XSTR];   // 34816 B: x[token][e] <-> hT[e][token]
  __shared__ float s_pool[4 * EMB];                  // 2048 B: pooled partials per item

  const int tid  = threadIdx.x;
  const int lane = tid & 63;
  const int wv   = tid >> 6;
  const int col  = lane & 15;
  const int quad = lane >> 4;
  const int b    = blockIdx.x * 4 + wv;

  const float* orow = obs + (size_t)b * OBSL;
  short* xbase = &s_xh[(wv * NTOK) * XSTR];
  const short8  z8 = {0,0,0,0,0,0,0,0};
  const floatx4 fz = {0.f,0.f,0.f,0.f};

  // ---------------- P0: alive flags (register-only), zero-pad, float4 obs scatter ----------------
  float flag; float invc;
  {
    float araw = (lane < NTOK) ? orow[1024 + lane] : 0.f;
    bool alv = (lane < NTOK) && (araw >= 0.5f);
    unsigned long long m = __ballot(alv);
    int cnt = __popcll(m);
    flag = alv ? 1.f : 0.f;
    if (cnt == 0) { flag = (lane < NTOK) ? 1.f : 0.f; cnt = NTOK; }
    invc = 1.f / (float)cnt;
  }
  float alv8[8];                                    // alive of keys j = quad*8+jj (PV layout)
  #pragma unroll
  for (int jj = 0; jj < 8; ++jj) alv8[jj] = __shfl(flag, quad * 8 + jj);
  const float alvI0 = __shfl(flag, col);            // alive of token col / 16+col (pool layout)
  const float alvI1 = __shfl(flag, 16 + col);

  #pragma unroll
  for (int it = 0; it < 4; ++it) {                  // zero cols [0,64) of own 32 rows
    int c = it * 64 + lane;
    *(short8*)&xbase[(c >> 3) * XSTR + (c & 7) * 8] = z8;
  }
  // 1024 data floats = 256 float4; DV=40, DP=24 both %4==0 so a float4 never crosses a row
  #pragma unroll
  for (int it = 0; it < 4; ++it) {
    int i4 = it * 64 + lane;
    float4 v = *(const float4*)&orow[i4 * 4];
    int r, k;
    if (i4 < 160) { r = (i4 * 205) >> 11;  k = (i4 - r * 10) * 4; }              // /10 magic (i4<160)
    else { int t2 = i4 - 160; int q6 = (t2 * 171) >> 10; r = 16 + q6; k = 40 + (t2 - q6 * 6) * 4; } // /6 magic (t2<96)
    uint2v u; u.x = pk2(v.x, v.y); u.y = pk2(v.z, v.w);
    *(uint2v*)&xbase[r * XSTR + k] = u;
  }

  // ---------------- P1: embed  D[e][tok] = embT x xin, packed b64 store as x[tok][e] ----------------
  {
    short8 Bxin[2][2];                               // all xin frags before overwriting rows
    #pragma unroll
    for (int nt = 0; nt < 2; ++nt)
      #pragma unroll
      for (int kt = 0; kt < 2; ++kt)
        Bxin[nt][kt] = *(const short8*)&xbase[(nt * 16 + col) * XSTR + kt * 32 + quad * 8];
    const short* embT = wsb;
    #pragma unroll
    for (int mtE = 0; mtE < 8; ++mtE) {
      short8 A0 = *(const short8*)&embT[(mtE * 16 + col) * 64 + quad * 8];
      short8 A1 = *(const short8*)&embT[(mtE * 16 + col) * 64 + 32 + quad * 8];
      float4 bv4 = *(const float4*)&bv[mtE * 16 + quad * 4];
      float4 bp4 = *(const float4*)&bp[mtE * 16 + quad * 4];
      #pragma unroll
      for (int nt = 0; nt < 2; ++nt) {
        floatx4 acc = fz;
        acc = mfma16(A0, Bxin[nt][0], acc);
        acc = mfma16(A1, Bxin[nt][1], acc);
        float4 bb = nt ? bp4 : bv4;
        uint2v u; u.x = pk2(acc[0] + bb.x, acc[1] + bb.y); u.y = pk2(acc[2] + bb.z, acc[3] + bb.w);
        *(uint2v*)&xbase[(nt * 16 + col) * XSTR + mtE * 16 + quad * 4] = u;
      }
    }
  }

  // ---------------- GAT layers ----------------
  for (int L = 0; L < 2; ++L) {
    const short* wT  = wsb + 8192 + L * 16384;
    const float* gas = L ? as1 : as0;
    const float* gad = L ? ad1 : ad0;

    // all x B-frags into regs before hT overwrites other strips
    short8 Bx[4][2];
    #pragma unroll
    for (int kt = 0; kt < 4; ++kt)
      #pragma unroll
      for (int nt = 0; nt < 2; ++nt)
        Bx[kt][nt] = *(const short8*)&xbase[(nt * 16 + col) * XSTR + kt * 32 + quad * 8];
    __syncthreads();                                 // barrier #1: x reads done before hT writes

    // hT[e][tok] = wT x xT, in 2 mt-groups of 4 (register budget)
    float psrc[4][2], pdst[4][2];
    #pragma unroll
    for (int hh = 0; hh < 4; ++hh) { psrc[hh][0]=0.f; psrc[hh][1]=0.f; pdst[hh][0]=0.f; pdst[hh][1]=0.f; }
    #pragma unroll
    for (int g = 0; g < 2; ++g) {
      floatx4 acc[4][2];
      #pragma unroll
      for (int mi = 0; mi < 4; ++mi) { acc[mi][0] = fz; acc[mi][1] = fz; }
      #pragma unroll
      for (int mi = 0; mi < 4; ++mi) {
        const int mt = g * 4 + mi;
        const short* wrow = &wT[(mt * 16 + col) * 128 + quad * 8];
        short8 A0 = *(const short8*)&wrow[0];
        short8 A1 = *(const short8*)&wrow[32];
        short8 A2 = *(const short8*)&wrow[64];
        short8 A3 = *(const short8*)&wrow[96];
        #pragma unroll
        for (int nt = 0; nt < 2; ++nt) {
          acc[mi][nt] = mfma16(A0, Bx[0][nt], acc[mi][nt]);
          acc[mi][nt] = mfma16(A1, Bx[1][nt], acc[mi][nt]);
          acc[mi][nt] = mfma16(A2, Bx[2][nt], acc[mi][nt]);
          acc[mi][nt] = mfma16(A3, Bx[3][nt], acc[mi][nt]);
        }
      }
      #pragma unroll
      for (int mi = 0; mi < 4; ++mi) {
        const int mt = g * 4 + mi;
        const int hh = mt >> 1;
        float4 cs = *(const float4*)&gas[mt * 16 + quad * 4];
        float4 cd = *(const float4*)&gad[mt * 16 + quad * 4];
        #pragma unroll
        for (int nt = 0; nt < 2; ++nt) {
          floatx4 a = acc[mi][nt];
          psrc[hh][nt] += a[0]*cs.x + a[1]*cs.y + a[2]*cs.z + a[3]*cs.w;
          pdst[hh][nt] += a[0]*cd.x + a[1]*cd.y + a[2]*cd.z + a[3]*cd.w;
          unsigned u01 = pk2(a[0], a[1]);
          unsigned u23 = pk2(a[2], a[3]);
          unsigned short* hrow = (unsigned short*)&s_xh[(mt * 16 + quad * 4) * XSTR + wv * NTOK + nt * 16 + col];
          hrow[0]        = (unsigned short)u01;
          hrow[XSTR]     = (unsigned short)(u01 >> 16);
          hrow[2 * XSTR] = (unsigned short)u23;
          hrow[3 * XSTR] = (unsigned short)(u23 >> 16);
        }
      }
    }

    // full per-token alpha in every lane (token = nt*16 + col), scaled to exp2 domain
    #pragma unroll
    for (int hh = 0; hh < 4; ++hh)
      #pragma unroll
      for (int nt = 0; nt < 2; ++nt) {
        float vs = psrc[hh][nt]; vs += __shfl_xor(vs, 16); vs += __shfl_xor(vs, 32);
        psrc[hh][nt] = vs * 1.44269504088896340736f;
        float vd = pdst[hh][nt]; vd += __shfl_xor(vd, 16); vd += __shfl_xor(vd, 32);
        pdst[hh][nt] = vd * 1.44269504088896340736f;
      }

    // softmax in PV B-frag layout: lane owns (i = ii*16+col, j = quad*8+jj)
    // exp2 domain, no max-subtract (alphas O(1)-bounded), mask folded into ad8
    short8 pf[4][2];
    #pragma unroll
    for (int hh = 0; hh < 4; ++hh) {
      float vsel = (quad >> 1) ? pdst[hh][1] : pdst[hh][0];
      float ad8[8];
      #pragma unroll
      for (int jj = 0; jj < 8; ++jj) {
        float v = __shfl(vsel, ((quad >> 1) << 5) + ((quad & 1) << 3) + jj);
        ad8[jj] = (alv8[jj] >= 0.5f) ? v : -1e30f;   // dead keys -> exp2 -> 0
      }
      #pragma unroll
      for (int ii = 0; ii < 2; ++ii) {
        float ai = psrc[hh][ii];
        float ev[8]; float sum = 0.f;
        #pragma unroll
        for (int jj = 0; jj < 8; ++jj) {
          float e = ai + ad8[jj];
          e = fmaxf(e, 0.2f * e);                    // leaky-relu (commutes with log2e scale)
          float p = exp2_hw(e);
          ev[jj] = p; sum += p;
        }
        sum += __shfl_xor(sum, 16);
        sum += __shfl_xor(sum, 32);
        float inv = rcp_hw(sum);
        union { unsigned u4[4]; short8 s; } pu;
        #pragma unroll
        for (int p2 = 0; p2 < 4; ++p2) pu.u4[p2] = pk2(ev[2*p2] * inv, ev[2*p2+1] * inv);
        pf[hh][ii] = pu.s;
      }
    }

    // PV A-frags (hT own column strip), then single barrier, then MFMA + direct epilogue
    short8 Ah[4][2];
    #pragma unroll
    for (int hh = 0; hh < 4; ++hh)
      #pragma unroll
      for (int mtE = 0; mtE < 2; ++mtE)
        Ah[hh][mtE] = *(const short8*)&s_xh[(hh * 32 + mtE * 16 + col) * XSTR + wv * NTOK + quad * 8];
    if (L == 0) __syncthreads();                     // barrier #2: hT reads done before x_next writes

    #pragma unroll
    for (int hh = 0; hh < 4; ++hh)
      #pragma unroll
      for (int mtE = 0; mtE < 2; ++mtE) {
        floatx4 po[2];
        #pragma unroll
        for (int nt = 0; nt < 2; ++nt) {
          po[nt] = mfma16(Ah[hh][mtE], pf[hh][nt], fz);
        }
        if (L == 0) {
          #pragma unroll
          for (int nt = 0; nt < 2; ++nt) {
            uint2v u;
            u.x = pk2(elu1(po[nt][0]), elu1(po[nt][1]));
            u.y = pk2(elu1(po[nt][2]), elu1(po[nt][3]));
            *(uint2v*)&xbase[(nt * 16 + col) * XSTR + hh * 32 + mtE * 16 + quad * 4] = u;
          }
        } else {
          #pragma unroll
          for (int r = 0; r < 4; ++r) {
            float s = elu1(po[0][r]) * alvI0 + elu1(po[1][r]) * alvI1;
            s += __shfl_xor(s, 1); s += __shfl_xor(s, 2);
            s += __shfl_xor(s, 4); s += __shfl_xor(s, 8);
            if (col == 0) s_pool[wv * EMB + hh * 32 + mtE * 16 + quad * 4 + r] = s;
          }
        }
      }
  }

  // ---------------- pooled output (same-wave LDS, no barrier) ----------------
  float r0 = s_pool[wv * EMB + lane];
  float r1 = s_pool[wv * EMB + 64 + lane];
  out[(size_t)b * EMB + lane]      = r0 * invc;
  out[(size_t)b * EMB + 64 + lane] = r1 * invc;
}

extern "C" void kernel_launch(void* const* d_in, const int* in_sizes, int n_in,
                              void* d_out, int out_size, void* d_ws, size_t ws_size,
                              hipStream_t stream) {
  const float* obs = (const float*)d_in[0];
  const float* Wv  = (const float*)d_in[1];
  const float* bv  = (const float*)d_in[2];
  const float* Wp  = (const float*)d_in[3];
  const float* bp  = (const float*)d_in[4];
  const float* w0  = (const float*)d_in[5];
  const float* as0 = (const float*)d_in[6];
  const float* ad0 = (const float*)d_in[7];
  const float* w1  = (const float*)d_in[8];
  const float* as1 = (const float*)d_in[9];
  const float* ad1 = (const float*)d_in[10];
  float* out = (float*)d_out;
  short* wsb = (short*)d_ws;                      // uses exactly 80 KiB

  int Bn = in_sizes[0] / OBSL;                    // 4096
  prep_weights<<<160, 256, 0, stream>>>(Wv, Wp, w0, w1, wsb);
  gnn_fused<<<Bn / 4, 256, 0, stream>>>(obs, bv, bp, as0, ad0, as1, ad1, wsb, out);
}